// Round 3
// baseline (15.514 us; speedup 1.0000x reference)
//
#include <hip/hip_runtime.h>
#include <hip/hip_bf16.h>

// Heatmap generation: out[b][h][w] = sum_l exp(-((w-x_l)^2+(h-y_l)^2)/(2*sigma^2))
// Separable: = sum_l gy[l][h] * gx[l][w]  (sum of 98 rank-1 outer products).
//
// Dtypes (established rounds 0-2): input X is f32, output is f32.
//  - bf16 input cast gave NaN (f32 bits misread as bf16 coords) -> input f32.
//  - bf16 packed output gave err 5.3245 == max ref over SECOND half of buffer
//    (we only filled 4 of 8 MB) -> output buffer is f32.
//
// Grid: 128 batches x 4 row-tiles (32 rows each) = 512 blocks, 256 threads.
// LDS: gx[98][128] (50 KB) + gy[98][32] (12.5 KB) -> 2 blocks/CU.
// Each thread computes a 4x4 pixel tile: per landmark 2x float4 LDS read + 16 FMA.

#define NB 128
#define NL 98
#define NW 128
#define NH 128
#define ROWS_PER_BLOCK 32
#define SIGMA 5.0f

__global__ __launch_bounds__(256, 2)
void heatmap_kernel(const float* __restrict__ X, float* __restrict__ out) {
    const int b    = blockIdx.x >> 2;                 // batch index
    const int row0 = (blockIdx.x & 3) * ROWS_PER_BLOCK;
    const int tid  = threadIdx.x;

    __shared__ float lmx[NL];
    __shared__ float lmy[NL];
    __shared__ float gx[NL][NW];              // 98*128*4 = 50176 B
    __shared__ float gy[NL][ROWS_PER_BLOCK]; // 98*32*4  = 12544 B

    // Load landmark coords: X[b][2l] = x, X[b][2l+1] = y
    if (tid < 2 * NL) {
        float v = X[(size_t)b * 2 * NL + tid];
        if (tid & 1) lmy[tid >> 1] = v;
        else         lmx[tid >> 1] = v;
    }
    __syncthreads();

    const float inv2s2 = 1.0f / (2.0f * SIGMA * SIGMA);  // 0.02

    // Fill gx: 98*128 = 12544 entries, 49 per thread
    for (int i = tid; i < NL * NW; i += 256) {
        int l = i >> 7;          // /128
        int w = i & 127;
        float d = (float)w - lmx[l];
        gx[l][w] = __expf(-d * d * inv2s2);
    }
    // Fill gy: 98*32 = 3136 entries
    for (int i = tid; i < NL * ROWS_PER_BLOCK; i += 256) {
        int l = i >> 5;          // /32
        int r = i & 31;
        float d = (float)(row0 + r) - lmy[l];
        gy[l][r] = __expf(-d * d * inv2s2);
    }
    __syncthreads();

    // Thread tile: 32 threads across cols (4 cols each), 8 down rows (4 rows each)
    const int tx = tid & 31;
    const int ty = tid >> 5;
    const int c0 = tx * 4;
    const int r0 = ty * 4;

    float acc[4][4];
    #pragma unroll
    for (int i = 0; i < 4; ++i)
        #pragma unroll
        for (int j = 0; j < 4; ++j)
            acc[i][j] = 0.0f;

    #pragma unroll 2
    for (int l = 0; l < NL; ++l) {
        float4 gxv = *reinterpret_cast<const float4*>(&gx[l][c0]);
        float4 gyv = *reinterpret_cast<const float4*>(&gy[l][r0]);
        float gxr[4] = {gxv.x, gxv.y, gxv.z, gxv.w};
        float gyr[4] = {gyv.x, gyv.y, gyv.z, gyv.w};
        #pragma unroll
        for (int i = 0; i < 4; ++i)
            #pragma unroll
            for (int j = 0; j < 4; ++j)
                acc[i][j] = fmaf(gyr[i], gxr[j], acc[i][j]);
    }

    // Store: 4 rows x float4 per thread (16 B/lane, coalesced, f32 output)
    #pragma unroll
    for (int i = 0; i < 4; ++i) {
        int row = row0 + r0 + i;
        float4 v = make_float4(acc[i][0], acc[i][1], acc[i][2], acc[i][3]);
        float* op = out + ((size_t)b * NH + row) * NW + c0;
        *reinterpret_cast<float4*>(op) = v;
    }
}

extern "C" void kernel_launch(void* const* d_in, const int* in_sizes, int n_in,
                              void* d_out, int out_size, void* d_ws, size_t ws_size,
                              hipStream_t stream) {
    const float* X = (const float*)d_in[0];
    float* out = (float*)d_out;
    dim3 grid(NB * (NH / ROWS_PER_BLOCK));   // 512 blocks
    dim3 block(256);
    heatmap_kernel<<<grid, block, 0, stream>>>(X, out);
}

// Round 4
// 10.508 us; speedup vs baseline: 1.4764x; 1.4764x over previous
//
#include <hip/hip_runtime.h>
#include <hip/hip_bf16.h>

// Heatmap = sum of 98 rank-1 outer products = per-batch GEMM:
//   out[b] (128x128) = GY (128 rows x 98 lm) @ GX (98 lm x 128 cols)
// with GY[h][l] = exp(-(h-y_l)^2 c), GX[l][w] = exp(-(w-x_l)^2 c).
// MFMA mfma_f32_16x16x32_bf16, K padded 98->128 via sentinel landmarks at
// -1000 (exp underflows to exact 0 -> no masking).
//
// Fragments are computed DIRECTLY in registers (each lane evaluates the 8
// exps its fragment slot needs) -- no LDS tiles, no barriers in the loop.
// Layouts (cdna4 16x16x32 bf16):
//   A: lane l holds A[l&15][(l>>4)*8 + j], j=0..7
//   B: lane l holds B[(l>>4)*8 + j][l&15]
//   C/D: lane l reg r -> row=(l>>4)*4+r, col=l&15   [m89-verified]
//
// Grid: 128 batches x 4 row-blocks(32 rows) = 512 blocks, 256 thr (4 waves).
// Wave w owns cols [w*32, w*32+32): M_rep=2, N_rep=2 16x16 C-tiles.
// Dtypes (established rounds 0-3): input f32, output f32.

#define NB 128
#define NL 98
#define NW 128
#define NH 128
#define SIGMA 5.0f

typedef __attribute__((ext_vector_type(8))) short short8;
typedef __attribute__((ext_vector_type(4))) float f32x4;

__global__ __launch_bounds__(256, 2)
void heatmap_mfma(const float* __restrict__ X, float* __restrict__ out) {
    const int b    = blockIdx.x >> 2;                 // batch
    const int row0 = (blockIdx.x & 3) * 32;           // row-block base
    const int tid  = threadIdx.x;
    const int wid  = tid >> 6;                        // wave id 0..3 -> col group
    const int lane = tid & 63;
    const int l16  = lane & 15;
    const int kg   = lane >> 4;                       // k-group 0..3

    // Stage landmark coords; pad [98,128) with sentinel -1000 -> exp == 0.
    __shared__ float lmraw[256];
    if (tid < 2 * NL) lmraw[tid] = X[(size_t)b * 2 * NL + tid];
    else if (tid < 256) lmraw[tid] = -1000.0f;
    __syncthreads();
    const float2* lm2 = (const float2*)lmraw;         // lm2[k] = (x_k, y_k)

    const float c = 1.0f / (2.0f * SIGMA * SIGMA);    // 0.02
    const int colw = wid * 32;

    f32x4 acc[2][2] = {};                             // [m][n], static-indexed

    #pragma unroll
    for (int ks = 0; ks < 4; ++ks) {
        const int k0 = ks * 32 + kg * 8;              // this lane's k base
        float xv[8], yv[8];
        #pragma unroll
        for (int j = 0; j < 8; ++j) {
            float2 p = lm2[k0 + j];                   // broadcast-ish LDS read
            xv[j] = p.x; yv[j] = p.y;
        }

        // A fragments: gy for rows row0 + m*16 + l16
        short8 afrag[2];
        #pragma unroll
        for (int m = 0; m < 2; ++m) {
            const float row = (float)(row0 + m * 16 + l16);
            #pragma unroll
            for (int j = 0; j < 8; ++j) {
                float d = row - yv[j];
                float g = __expf(-d * d * c);
                __hip_bfloat16 h = __float2bfloat16(g);
                afrag[m][j] = *reinterpret_cast<short*>(&h);
            }
        }
        // B fragments: gx for cols colw + n*16 + l16
        short8 bfrag[2];
        #pragma unroll
        for (int n = 0; n < 2; ++n) {
            const float col = (float)(colw + n * 16 + l16);
            #pragma unroll
            for (int j = 0; j < 8; ++j) {
                float d = col - xv[j];
                float g = __expf(-d * d * c);
                __hip_bfloat16 h = __float2bfloat16(g);
                bfrag[n][j] = *reinterpret_cast<short*>(&h);
            }
        }

        #pragma unroll
        for (int m = 0; m < 2; ++m)
            #pragma unroll
            for (int n = 0; n < 2; ++n)
                acc[m][n] = __builtin_amdgcn_mfma_f32_16x16x32_bf16(
                    afrag[m], bfrag[n], acc[m][n], 0, 0, 0);
    }

    // Epilogue: C/D layout col=l16, row=kg*4+r per 16x16 tile.
    #pragma unroll
    for (int m = 0; m < 2; ++m)
        #pragma unroll
        for (int n = 0; n < 2; ++n)
            #pragma unroll
            for (int r = 0; r < 4; ++r) {
                int row = row0 + m * 16 + kg * 4 + r;
                int col = colw + n * 16 + l16;
                out[((size_t)b * NH + row) * NW + col] = acc[m][n][r];
            }
}

extern "C" void kernel_launch(void* const* d_in, const int* in_sizes, int n_in,
                              void* d_out, int out_size, void* d_ws, size_t ws_size,
                              hipStream_t stream) {
    const float* X = (const float*)d_in[0];
    float* out = (float*)d_out;
    dim3 grid(NB * 4);    // 512 blocks
    dim3 block(256);
    heatmap_mfma<<<grid, block, 0, stream>>>(X, out);
}